// Round 23
// baseline (96.835 us; speedup 1.0000x reference)
//
#include <hip/hip_runtime.h>

#define BN 131072   // B*N nodes
#define BE 2097152  // edges
#define NGR 64      // graphs
#define CAP 36864   // per-graph slab capacity (mean 32768, sigma~180)

// ws layout (bytes):
#define XS_OFF     0          // Xs   [64][16][64] f   = 262144
#define WACC_OFF   262144     // wacc [64][16] f       = 4096
#define A_OFF      266240     // A    [64][16][16] f   = 65536  -> 331776
#define ZERO_U4    20736      // 331776 / 16
#define CUR_OFF    331776     // cur  [64] int  -> 332032
#define QS_OFF     332032     // qs  [256] int  -> 333056
#define ENDS_OFF   333056     // ends4 [256][2048] int = 2097152 -> 2430208
#define SH_OFF     2430208    // Sh [131072][16] bf16  = 4194304 -> 6624512
#define PK_OFF     6624512    // packed [64][CAP] u32  = 9437184 -> 16061696

__device__ __forceinline__ float bflo(unsigned u) { return __uint_as_float(u << 16); }
__device__ __forceinline__ float bfhi(unsigned u) { return __uint_as_float(u & 0xFFFF0000u); }
__device__ __forceinline__ unsigned bfpack(float a, float b) {
    unsigned b0 = __float_as_uint(a);
    unsigned b1 = __float_as_uint(b);
    unsigned h0 = (b0 + 0x7FFFu + ((b0 >> 16) & 1u)) >> 16;
    unsigned h1 = (b1 + 0x7FFFu + ((b1 >> 16) & 1u)) >> 16;
    return h0 | (h1 << 16);
}

// ------- zero accumulators; init slab cursors ----------------------------------
__global__ __launch_bounds__(256) void k_zero(uint4* __restrict__ zbase,
                                              int* __restrict__ cur)
{
    int zi = blockIdx.x * 256 + threadIdx.x;
    if (zi < ZERO_U4) zbase[zi] = make_uint4(0u, 0u, 0u, 0u);
    if (blockIdx.x == 0 && threadIdx.x < NGR) cur[threadIdx.x] = threadIdx.x * CAP;
}

// ------- level-1 scatter into fixed per-graph slabs, packed (e0l<<17 | e1) -----
__global__ __launch_bounds__(256) void k_scatter(const int* __restrict__ e_,
                                                 int* __restrict__ cur,
                                                 unsigned* __restrict__ packed)
{
    __shared__ int h[64];
    __shared__ int gb[64];
    int t = threadIdx.x;
    if (t < 64) h[t] = 0;
    __syncthreads();
    size_t base = (size_t)blockIdx.x * 4096;     // 512 blocks
    int e0v[16], e1v[16], rk[16];
    #pragma unroll
    for (int k = 0; k < 16; ++k) {
        size_t i = base + k * 256 + t;
        e0v[k] = e_[i];
        e1v[k] = e_[BE + i];
        rk[k] = atomicAdd(&h[e0v[k] >> 11], 1);
    }
    __syncthreads();
    if (t < 64) gb[t] = atomicAdd(&cur[t], h[t]);
    __syncthreads();
    #pragma unroll
    for (int k = 0; k < 16; ++k) {
        int b = e0v[k] >> 11;
        packed[gb[b] + rk[k]] = ((unsigned)(e0v[k] & 2047) << 17) | (unsigned)e1v[k];
    }
}

// ------- fused: blocks 0..255 = sortL (no sbuf); 256..1279 = node v2 -----------
__global__ __launch_bounds__(256) void k_nodeSort(const float* __restrict__ x,
                                                  const float* __restrict__ Wa,
                                                  const float* __restrict__ ba,
                                                  unsigned short* __restrict__ Sh,
                                                  float* __restrict__ Xs,
                                                  float* __restrict__ wacc,
                                                  unsigned* __restrict__ packed,
                                                  const int* __restrict__ cur,
                                                  int* __restrict__ qs,
                                                  int* __restrict__ ends4)
{
    __shared__ __align__(16) unsigned char smem[47616];
    const int t = threadIdx.x;
    const int blk = blockIdx.x;

    if (blk < 256) {
        // ---------------- sortL branch: LDS counting sort, 2-pass global read ----
        unsigned* sout = (unsigned*)smem;              // 36864 B
        int* h    = (int*)(smem + 36864);              //  8192 B -> 45056
        int* psum = (int*)(smem + 45056);              //  1024 B -> 46080
        const int Q = blk;                 // g*4+q
        const int g = Q >> 2;
        const int q = Q & 3;
        const int slab = g * CAP;
        const int n = cur[g] - slab;
        const int chunk = (n + 3) >> 2;
        const int qlo = slab + min(q * chunk, n);
        const int qhi = slab + min((q + 1) * chunk, n);
        const int nq = qhi - qlo;
        if (t == 0) qs[Q] = qlo;

        for (int i = t; i < 2048; i += 256) h[i] = 0;
        __syncthreads();
        for (int i = t; i < nq; i += 256) {
            atomicAdd(&h[packed[qlo + i] >> 17], 1);
        }
        __syncthreads();

        int hl[8]; int s = 0;
        #pragma unroll
        for (int j = 0; j < 8; ++j) { hl[j] = h[t * 8 + j]; s += hl[j]; }
        psum[t] = s;
        __syncthreads();
        for (int off = 1; off < 256; off <<= 1) {
            int v = (t >= off) ? psum[t - off] : 0;
            __syncthreads();
            psum[t] += v;
            __syncthreads();
        }
        int run = psum[t] - s;
        int* ends = ends4 + (Q << 11);
        #pragma unroll
        for (int j = 0; j < 8; ++j) {
            int bin = t * 8 + j;
            int c = hl[j];
            h[bin] = run;
            run += c;
            ends[bin] = qlo + run;
        }
        __syncthreads();
        for (int i = t; i < nq; i += 256) {
            unsigned u = packed[qlo + i];
            int pos = atomicAdd(&h[u >> 17], 1);
            sout[pos] = u & 131071u;
        }
        __syncthreads();
        for (int i = t; i < nq; i += 256) packed[qlo + i] = sout[i];
        return;
    }

    // ---------------- node branch (v2): 256 threads, 128 nodes ----------------
    const int nblk = blk - 256;           // 0..1023
    const int g = nblk >> 4;
    float* Xl = (float*)smem;             // [128*65] f = 33280 B
    float* Sl = (float*)(smem + 33280);   // [128*20] f = 10240 B
    float* Wl = (float*)(smem + 43520);   // [64*16]  f = 4096 B
    const int nd = t & 127;               // node
    const int ch = t >> 7;                // c-range half (0 or 1)

    const float4* xg4 = (const float4*)(x + (size_t)nblk * 128 * 64);
    #pragma unroll
    for (int it = 0; it < 8; ++it) {
        int idx4 = it * 256 + t;
        float4 v = xg4[idx4];
        int node = idx4 >> 4;
        int c4 = (idx4 & 15) * 4;
        float* p = &Xl[node * 65 + c4];
        p[0] = v.x; p[1] = v.y; p[2] = v.z; p[3] = v.w;
    }
    for (int i = t; i < 1024; i += 256) Wl[i] = Wa[i];
    __syncthreads();

    float lg[16];
    #pragma unroll
    for (int m = 0; m < 16; ++m) lg[m] = 0.f;
    const int c0 = ch * 32;
    for (int c = c0; c < c0 + 32; ++c) {
        float xc = Xl[nd * 65 + c];
        #pragma unroll
        for (int m = 0; m < 16; ++m) lg[m] += xc * Wl[c * 16 + m];
    }
    float* Pl = Sl;                    // reuse Sl region for partials [128][17]
    if (ch == 1) {
        #pragma unroll
        for (int m = 0; m < 16; ++m) Pl[nd * 17 + m] = lg[m];
    }
    __syncthreads();

    float s[16];
    if (ch == 0) {
        float sum = 0.f, mx;
        #pragma unroll
        for (int m = 0; m < 16; ++m) lg[m] += ba[m] + Pl[nd * 17 + m];
        mx = lg[0];
        #pragma unroll
        for (int m = 1; m < 16; ++m) mx = fmaxf(mx, lg[m]);
        #pragma unroll
        for (int m = 0; m < 16; ++m) { s[m] = __expf(lg[m] - mx); sum += s[m]; }
        float inv = 1.f / sum;
        #pragma unroll
        for (int m = 0; m < 16; ++m) s[m] *= inv;

        unsigned pk8[8];
        #pragma unroll
        for (int j = 0; j < 8; ++j) pk8[j] = bfpack(s[2*j], s[2*j+1]);
        uint4* hrow = (uint4*)(Sh + ((size_t)nblk * 128 + nd) * 16);
        hrow[0] = make_uint4(pk8[0], pk8[1], pk8[2], pk8[3]);
        hrow[1] = make_uint4(pk8[4], pk8[5], pk8[6], pk8[7]);
    }
    __syncthreads();   // partial reads complete before Sl overwrite
    if (ch == 0) {
        #pragma unroll
        for (int q = 0; q < 4; ++q)
            *(float4*)(&Sl[nd * 20 + q * 4]) = make_float4(s[q*4], s[q*4+1], s[q*4+2], s[q*4+3]);
    }
    __syncthreads();

    const int c = t & 63;
    const int mg = t >> 6;            // m-quad 0..3
    float a0 = 0.f, a1 = 0.f, a2 = 0.f, a3 = 0.f;
    for (int n = 0; n < 128; ++n) {
        float xv = Xl[n * 65 + c];
        float4 sa = *(const float4*)(&Sl[n * 20 + mg * 4]);
        a0 += sa.x * xv; a1 += sa.y * xv; a2 += sa.z * xv; a3 += sa.w * xv;
    }
    float* xsg = Xs + g * 1024 + (mg * 4) * 64 + c;
    atomicAdd(&xsg[0],   a0);
    atomicAdd(&xsg[64],  a1);
    atomicAdd(&xsg[128], a2);
    atomicAdd(&xsg[192], a3);

    if (t < 16) {
        float ws_ = 0.f;
        for (int n = 0; n < 128; ++n) ws_ += Sl[n * 20 + t];
        atomicAdd(&wacc[g * 16 + t], ws_);
    }
}

// ------- fused: blocks 0..255 = x_out rows; 256..2303 = edge v3 ----------------
__global__ __launch_bounds__(256) void k_edgeX(const unsigned* __restrict__ se1,
                                               const unsigned short* __restrict__ Sh,
                                               const int* __restrict__ ends4,
                                               const int* __restrict__ qs,
                                               float* __restrict__ A,
                                               const float* __restrict__ Xs,
                                               const float* __restrict__ wacc,
                                               const float* __restrict__ We,
                                               const float* __restrict__ be,
                                               float* __restrict__ out)
{
    __shared__ __align__(16) unsigned char smem[15616];
    const int t = threadIdx.x;
    const int blk = blockIdx.x;

    if (blk < 256) {
        // ---------------- x_out branch ----------------
        float* WeL = (float*)smem;   // [64*61] f = 15616 B
        for (int i = t; i < 64 * 61; i += 256) WeL[i] = We[i];
        __syncthreads();
        int lane = t & 63;
        int row = blk * 4 + (t >> 6);
        const float* xs = Xs + row * 64;
        float w = wacc[row];
        float val;
        if (lane < 3) {
            val = xs[lane] / fmaxf(w, 1e-10f);
        } else {
            int c2 = lane - 3;
            float accv = w * be[c2];
            for (int cc = 0; cc < 64; ++cc) accv += xs[cc] * WeL[cc * 61 + c2];
            val = accv;
        }
        out[row * 64 + lane] = val;
        return;
    }

    // ---------------- edge branch: 4 lanes/edge, ends prefetch, 4-wide unroll ---
    float* ASl = (float*)smem;       // [64*16] f = 4096 B
    const int eblk = blk - 256;           // 0..2047, 64 nodes each
    const int g = eblk >> 5;
    const int nbase = eblk << 6;

    {
        const int qd = t >> 2;
        const int c4 = (t & 3) << 2;
        const int nl = (nbase & 2047) + qd;
        const unsigned short* __restrict__ ShB = Sh + c4;

        int lo[4], hi[4];
        #pragma unroll
        for (int q = 0; q < 4; ++q) {
            const int Qb = (g << 2) + q;
            const int* __restrict__ ends = ends4 + (Qb << 11);
            lo[q] = nl ? ends[nl - 1] : qs[Qb];
            hi[q] = ends[nl];
        }

        float a0 = 0.f, a1 = 0.f, a2 = 0.f, a3 = 0.f;
        #pragma unroll
        for (int q = 0; q < 4; ++q) {
            int i = lo[q];
            const int h2 = hi[q];
            for (; i + 4 <= h2; i += 4) {
                unsigned ea = se1[i];
                unsigned eb = se1[i + 1];
                unsigned ec = se1[i + 2];
                unsigned ed = se1[i + 3];
                uint2 ra = *(const uint2*)(ShB + ((size_t)ea << 4));
                uint2 rb = *(const uint2*)(ShB + ((size_t)eb << 4));
                uint2 rc = *(const uint2*)(ShB + ((size_t)ec << 4));
                uint2 rd = *(const uint2*)(ShB + ((size_t)ed << 4));
                a0 += bflo(ra.x) + bflo(rb.x) + bflo(rc.x) + bflo(rd.x);
                a1 += bfhi(ra.x) + bfhi(rb.x) + bfhi(rc.x) + bfhi(rd.x);
                a2 += bflo(ra.y) + bflo(rb.y) + bflo(rc.y) + bflo(rd.y);
                a3 += bfhi(ra.y) + bfhi(rb.y) + bfhi(rc.y) + bfhi(rd.y);
            }
            for (; i < h2; ++i) {
                unsigned ea = se1[i];
                uint2 ra = *(const uint2*)(ShB + ((size_t)ea << 4));
                a0 += bflo(ra.x); a1 += bfhi(ra.x); a2 += bflo(ra.y); a3 += bfhi(ra.y);
            }
        }
        *(float4*)(&ASl[qd * 16 + c4]) = make_float4(a0, a1, a2, a3);
    }
    __syncthreads();

    {
        const int m = t >> 4;
        const int k = t & 15;
        const unsigned short* __restrict__ SgM = Sh + ((size_t)nbase << 4) + m;
        float a = 0.f;
        #pragma unroll 4
        for (int i = 0; i < 64; ++i) {
            float sv = __uint_as_float((unsigned)SgM[(size_t)i << 4] << 16);
            a += sv * ASl[i * 16 + k];
        }
        atomicAdd(&A[(g << 8) + t], a);
    }
}

// ------- top-k(4) of A rows -> e_out, b_out ------------------------------------
__global__ __launch_bounds__(256) void k_topk(const float* __restrict__ A,
                                              float* __restrict__ out)
{
    int r = blockIdx.x * 256 + threadIdx.x;   // 0..1023  (= g*16 + m)
    float v[16];
    #pragma unroll
    for (int i = 0; i < 16; ++i) v[i] = A[r * 16 + i];
    float* e0o = out + 65536;
    float* e1o = out + 65536 + 4096;
    float* bo  = out + 65536 + 8192;
    unsigned mask = 0;
    #pragma unroll
    for (int rep = 0; rep < 4; ++rep) {
        float best = -3.4e38f; int bi = 0;
        #pragma unroll
        for (int i = 0; i < 16; ++i) {
            bool ok = (((mask >> i) & 1u) == 0u) && (v[i] > best);
            if (ok) { best = v[i]; bi = i; }
        }
        mask |= (1u << bi);
        e0o[r * 4 + rep] = (float)r;
        e1o[r * 4 + rep] = (float)((r & ~15) + bi);
    }
    bo[r] = (float)(r >> 4);
}

extern "C" void kernel_launch(void* const* d_in, const int* in_sizes, int n_in,
                              void* d_out, int out_size, void* d_ws, size_t ws_size,
                              hipStream_t stream)
{
    const float* x  = (const float*)d_in[0];
    const int*   e  = (const int*)d_in[1];
    const float* Wa = (const float*)d_in[3];
    const float* ba = (const float*)d_in[4];
    const float* We = (const float*)d_in[5];
    const float* be = (const float*)d_in[6];

    char* ws = (char*)d_ws;
    float* Xs     = (float*)(ws + XS_OFF);
    float* wacc   = (float*)(ws + WACC_OFF);
    float* A      = (float*)(ws + A_OFF);
    int*   cur    = (int*)(ws + CUR_OFF);
    int*   qs     = (int*)(ws + QS_OFF);
    int*   ends4  = (int*)(ws + ENDS_OFF);
    unsigned short* Sh = (unsigned short*)(ws + SH_OFF);
    unsigned* packed = (unsigned*)(ws + PK_OFF);

    k_zero    <<<82, 256, 0, stream>>>((uint4*)ws, cur);
    k_scatter <<<512, 256, 0, stream>>>(e, cur, packed);
    k_nodeSort<<<1280, 256, 0, stream>>>(x, Wa, ba, Sh, Xs, wacc, packed, cur, qs, ends4);
    k_edgeX   <<<2304, 256, 0, stream>>>(packed, Sh, ends4, qs, A, Xs, wacc, We, be, (float*)d_out);
    k_topk    <<<4, 256, 0, stream>>>(A, (float*)d_out);
}

// Round 24
// 86.635 us; speedup vs baseline: 1.1177x; 1.1177x over previous
//
#include <hip/hip_runtime.h>

#define BN 131072   // B*N nodes
#define BE 2097152  // edges
#define NGR 64      // graphs
#define CAP 36864   // per-graph slab capacity (mean 32768, sigma~180)

// ws layout (bytes):
#define XS_OFF     0          // Xs   [64][16][64] f   = 262144
#define WACC_OFF   262144     // wacc [64][16] f       = 4096
#define A_OFF      266240     // A    [64][16][16] f   = 65536  -> 331776
#define ZERO_U4    20736      // 331776 / 16
#define CUR_OFF    331776     // cur  [64] int  -> 332032
#define QS_OFF     332032     // qs  [256] int  -> 333056
#define ENDS_OFF   333056     // ends4 [256][2048] int = 2097152 -> 2430208
#define SH_OFF     2430208    // Sh [131072][16] bf16  = 4194304 -> 6624512
#define PK_OFF     6624512    // packed [64][CAP] u32  = 9437184 -> 16061696

__device__ __forceinline__ float bflo(unsigned u) { return __uint_as_float(u << 16); }
__device__ __forceinline__ float bfhi(unsigned u) { return __uint_as_float(u & 0xFFFF0000u); }
__device__ __forceinline__ unsigned bfpack(float a, float b) {
    unsigned b0 = __float_as_uint(a);
    unsigned b1 = __float_as_uint(b);
    unsigned h0 = (b0 + 0x7FFFu + ((b0 >> 16) & 1u)) >> 16;
    unsigned h1 = (b1 + 0x7FFFu + ((b1 >> 16) & 1u)) >> 16;
    return h0 | (h1 << 16);
}

// ------- zero accumulators; init slab cursors ----------------------------------
__global__ __launch_bounds__(256) void k_zero(uint4* __restrict__ zbase,
                                              int* __restrict__ cur)
{
    int zi = blockIdx.x * 256 + threadIdx.x;
    if (zi < ZERO_U4) zbase[zi] = make_uint4(0u, 0u, 0u, 0u);
    if (blockIdx.x == 0 && threadIdx.x < NGR) cur[threadIdx.x] = threadIdx.x * CAP;
}

// ------- level-1 scatter (uint4 edge loads) into fixed per-graph slabs ---------
__global__ __launch_bounds__(256) void k_scatter(const int* __restrict__ e_,
                                                 int* __restrict__ cur,
                                                 unsigned* __restrict__ packed)
{
    __shared__ int h[64];
    __shared__ int gb[64];
    int t = threadIdx.x;
    if (t < 64) h[t] = 0;
    __syncthreads();
    size_t base = (size_t)blockIdx.x * 4096;     // 512 blocks
    const uint4* e0v4 = (const uint4*)(e_ + base);
    const uint4* e1v4 = (const uint4*)(e_ + BE + base);
    int e0v[16], e1v[16], rk[16];
    #pragma unroll
    for (int k4 = 0; k4 < 4; ++k4) {
        uint4 a = e0v4[k4 * 256 + t];
        uint4 b = e1v4[k4 * 256 + t];
        e0v[k4*4+0] = (int)a.x; e0v[k4*4+1] = (int)a.y;
        e0v[k4*4+2] = (int)a.z; e0v[k4*4+3] = (int)a.w;
        e1v[k4*4+0] = (int)b.x; e1v[k4*4+1] = (int)b.y;
        e1v[k4*4+2] = (int)b.z; e1v[k4*4+3] = (int)b.w;
    }
    #pragma unroll
    for (int k = 0; k < 16; ++k) {
        rk[k] = atomicAdd(&h[e0v[k] >> 11], 1);
    }
    __syncthreads();
    if (t < 64) gb[t] = atomicAdd(&cur[t], h[t]);
    __syncthreads();
    #pragma unroll
    for (int k = 0; k < 16; ++k) {
        int b = e0v[k] >> 11;
        packed[gb[b] + rk[k]] = ((unsigned)(e0v[k] & 2047) << 17) | (unsigned)e1v[k];
    }
}

// ------- fused: blocks 0..255 = sortL (no sbuf); 256..1279 = node v2 -----------
__global__ __launch_bounds__(256) void k_nodeSort(const float* __restrict__ x,
                                                  const float* __restrict__ Wa,
                                                  const float* __restrict__ ba,
                                                  unsigned short* __restrict__ Sh,
                                                  float* __restrict__ Xs,
                                                  float* __restrict__ wacc,
                                                  unsigned* __restrict__ packed,
                                                  const int* __restrict__ cur,
                                                  int* __restrict__ qs,
                                                  int* __restrict__ ends4)
{
    __shared__ __align__(16) unsigned char smem[47616];
    const int t = threadIdx.x;
    const int blk = blockIdx.x;

    if (blk < 256) {
        // ---------------- sortL branch: LDS counting sort, 2-pass global read ----
        unsigned* sout = (unsigned*)smem;              // 36864 B
        int* h    = (int*)(smem + 36864);              //  8192 B -> 45056
        int* psum = (int*)(smem + 45056);              //  1024 B -> 46080
        const int Q = blk;                 // g*4+q
        const int g = Q >> 2;
        const int q = Q & 3;
        const int slab = g * CAP;
        const int n = cur[g] - slab;
        const int chunk = (n + 3) >> 2;
        const int qlo = slab + min(q * chunk, n);
        const int qhi = slab + min((q + 1) * chunk, n);
        const int nq = qhi - qlo;
        if (t == 0) qs[Q] = qlo;

        for (int i = t; i < 2048; i += 256) h[i] = 0;
        __syncthreads();
        for (int i = t; i < nq; i += 256) {
            atomicAdd(&h[packed[qlo + i] >> 17], 1);
        }
        __syncthreads();

        int hl[8]; int s = 0;
        #pragma unroll
        for (int j = 0; j < 8; ++j) { hl[j] = h[t * 8 + j]; s += hl[j]; }
        psum[t] = s;
        __syncthreads();
        for (int off = 1; off < 256; off <<= 1) {
            int v = (t >= off) ? psum[t - off] : 0;
            __syncthreads();
            psum[t] += v;
            __syncthreads();
        }
        int run = psum[t] - s;
        int* ends = ends4 + (Q << 11);
        #pragma unroll
        for (int j = 0; j < 8; ++j) {
            int bin = t * 8 + j;
            int c = hl[j];
            h[bin] = run;
            run += c;
            ends[bin] = qlo + run;
        }
        __syncthreads();
        for (int i = t; i < nq; i += 256) {
            unsigned u = packed[qlo + i];
            int pos = atomicAdd(&h[u >> 17], 1);
            sout[pos] = u & 131071u;
        }
        __syncthreads();
        for (int i = t; i < nq; i += 256) packed[qlo + i] = sout[i];
        return;
    }

    // ---------------- node branch (v2): 256 threads, 128 nodes ----------------
    const int nblk = blk - 256;           // 0..1023
    const int g = nblk >> 4;
    float* Xl = (float*)smem;             // [128*65] f = 33280 B
    float* Sl = (float*)(smem + 33280);   // [128*20] f = 10240 B
    float* Wl = (float*)(smem + 43520);   // [64*16]  f = 4096 B
    const int nd = t & 127;               // node
    const int ch = t >> 7;                // c-range half (0 or 1)

    const float4* xg4 = (const float4*)(x + (size_t)nblk * 128 * 64);
    #pragma unroll
    for (int it = 0; it < 8; ++it) {
        int idx4 = it * 256 + t;
        float4 v = xg4[idx4];
        int node = idx4 >> 4;
        int c4 = (idx4 & 15) * 4;
        float* p = &Xl[node * 65 + c4];
        p[0] = v.x; p[1] = v.y; p[2] = v.z; p[3] = v.w;
    }
    for (int i = t; i < 1024; i += 256) Wl[i] = Wa[i];
    __syncthreads();

    float lg[16];
    #pragma unroll
    for (int m = 0; m < 16; ++m) lg[m] = 0.f;
    const int c0 = ch * 32;
    for (int c = c0; c < c0 + 32; ++c) {
        float xc = Xl[nd * 65 + c];
        #pragma unroll
        for (int m = 0; m < 16; ++m) lg[m] += xc * Wl[c * 16 + m];
    }
    float* Pl = Sl;                    // reuse Sl region for partials [128][17]
    if (ch == 1) {
        #pragma unroll
        for (int m = 0; m < 16; ++m) Pl[nd * 17 + m] = lg[m];
    }
    __syncthreads();

    float s[16];
    if (ch == 0) {
        float sum = 0.f, mx;
        #pragma unroll
        for (int m = 0; m < 16; ++m) lg[m] += ba[m] + Pl[nd * 17 + m];
        mx = lg[0];
        #pragma unroll
        for (int m = 1; m < 16; ++m) mx = fmaxf(mx, lg[m]);
        #pragma unroll
        for (int m = 0; m < 16; ++m) { s[m] = __expf(lg[m] - mx); sum += s[m]; }
        float inv = 1.f / sum;
        #pragma unroll
        for (int m = 0; m < 16; ++m) s[m] *= inv;

        unsigned pk8[8];
        #pragma unroll
        for (int j = 0; j < 8; ++j) pk8[j] = bfpack(s[2*j], s[2*j+1]);
        uint4* hrow = (uint4*)(Sh + ((size_t)nblk * 128 + nd) * 16);
        hrow[0] = make_uint4(pk8[0], pk8[1], pk8[2], pk8[3]);
        hrow[1] = make_uint4(pk8[4], pk8[5], pk8[6], pk8[7]);
    }
    __syncthreads();   // partial reads complete before Sl overwrite
    if (ch == 0) {
        #pragma unroll
        for (int q = 0; q < 4; ++q)
            *(float4*)(&Sl[nd * 20 + q * 4]) = make_float4(s[q*4], s[q*4+1], s[q*4+2], s[q*4+3]);
    }
    __syncthreads();

    const int c = t & 63;
    const int mg = t >> 6;            // m-quad 0..3
    float a0 = 0.f, a1 = 0.f, a2 = 0.f, a3 = 0.f;
    for (int n = 0; n < 128; ++n) {
        float xv = Xl[n * 65 + c];
        float4 sa = *(const float4*)(&Sl[n * 20 + mg * 4]);
        a0 += sa.x * xv; a1 += sa.y * xv; a2 += sa.z * xv; a3 += sa.w * xv;
    }
    float* xsg = Xs + g * 1024 + (mg * 4) * 64 + c;
    atomicAdd(&xsg[0],   a0);
    atomicAdd(&xsg[64],  a1);
    atomicAdd(&xsg[128], a2);
    atomicAdd(&xsg[192], a3);

    if (t < 16) {
        float ws_ = 0.f;
        for (int n = 0; n < 128; ++n) ws_ += Sl[n * 20 + t];
        atomicAdd(&wacc[g * 16 + t], ws_);
    }
}

// ------- edge kernel: 4 lanes/edge, ends prefetch, 4-wide gather unroll --------
__global__ __launch_bounds__(256) void k_edge(const unsigned* __restrict__ se1,
                                              const unsigned short* __restrict__ Sh,
                                              const int* __restrict__ ends4,
                                              const int* __restrict__ qs,
                                              float* __restrict__ A)
{
    __shared__ __align__(16) float ASl[64 * 16];
    const int t = threadIdx.x;
    const int blk = blockIdx.x;           // 2048 blocks, 64 nodes each
    const int g = blk >> 5;
    const int nbase = blk << 6;

    {
        const int qd = t >> 2;
        const int c4 = (t & 3) << 2;
        const int nl = (nbase & 2047) + qd;
        const unsigned short* __restrict__ ShB = Sh + c4;

        int lo[4], hi[4];
        #pragma unroll
        for (int q = 0; q < 4; ++q) {
            const int Qb = (g << 2) + q;
            const int* __restrict__ ends = ends4 + (Qb << 11);
            lo[q] = nl ? ends[nl - 1] : qs[Qb];
            hi[q] = ends[nl];
        }

        float a0 = 0.f, a1 = 0.f, a2 = 0.f, a3 = 0.f;
        #pragma unroll
        for (int q = 0; q < 4; ++q) {
            int i = lo[q];
            const int h2 = hi[q];
            for (; i + 4 <= h2; i += 4) {
                unsigned ea = se1[i];
                unsigned eb = se1[i + 1];
                unsigned ec = se1[i + 2];
                unsigned ed = se1[i + 3];
                uint2 ra = *(const uint2*)(ShB + ((size_t)ea << 4));
                uint2 rb = *(const uint2*)(ShB + ((size_t)eb << 4));
                uint2 rc = *(const uint2*)(ShB + ((size_t)ec << 4));
                uint2 rd = *(const uint2*)(ShB + ((size_t)ed << 4));
                a0 += bflo(ra.x) + bflo(rb.x) + bflo(rc.x) + bflo(rd.x);
                a1 += bfhi(ra.x) + bfhi(rb.x) + bfhi(rc.x) + bfhi(rd.x);
                a2 += bflo(ra.y) + bflo(rb.y) + bflo(rc.y) + bflo(rd.y);
                a3 += bfhi(ra.y) + bfhi(rb.y) + bfhi(rc.y) + bfhi(rd.y);
            }
            for (; i < h2; ++i) {
                unsigned ea = se1[i];
                uint2 ra = *(const uint2*)(ShB + ((size_t)ea << 4));
                a0 += bflo(ra.x); a1 += bfhi(ra.x); a2 += bflo(ra.y); a3 += bfhi(ra.y);
            }
        }
        *(float4*)(&ASl[qd * 16 + c4]) = make_float4(a0, a1, a2, a3);
    }
    __syncthreads();

    {
        const int m = t >> 4;
        const int k = t & 15;
        const unsigned short* __restrict__ SgM = Sh + ((size_t)nbase << 4) + m;
        float a = 0.f;
        #pragma unroll 4
        for (int i = 0; i < 64; ++i) {
            float sv = __uint_as_float((unsigned)SgM[(size_t)i << 4] << 16);
            a += sv * ASl[i * 16 + k];
        }
        atomicAdd(&A[(g << 8) + t], a);
    }
}

// ------- fused epilogue: blocks 0..255 = x_out rows; blocks 256..259 = top-k ---
__global__ __launch_bounds__(256) void k_xt(const float* __restrict__ Xs,
                                            const float* __restrict__ wacc,
                                            const float* __restrict__ We,
                                            const float* __restrict__ be,
                                            const float* __restrict__ A,
                                            float* __restrict__ out)
{
    __shared__ float WeL[64 * 61];   // 15616 B
    const int t = threadIdx.x;
    const int blk = blockIdx.x;
    for (int i = t; i < 64 * 61; i += 256) WeL[i] = We[i];
    __syncthreads();

    if (blk < 256) {
        int lane = t & 63;
        int row = blk * 4 + (t >> 6);
        const float* xs = Xs + row * 64;
        float w = wacc[row];
        float val;
        if (lane < 3) {
            val = xs[lane] / fmaxf(w, 1e-10f);
        } else {
            int c2 = lane - 3;
            float accv = w * be[c2];
            for (int cc = 0; cc < 64; ++cc) accv += xs[cc] * WeL[cc * 61 + c2];
            val = accv;
        }
        out[row * 64 + lane] = val;
    } else {
        int r = (blk - 256) * 256 + t;    // 0..1023
        float v[16];
        #pragma unroll
        for (int i = 0; i < 16; ++i) v[i] = A[r * 16 + i];
        float* e0o = out + 65536;
        float* e1o = out + 65536 + 4096;
        float* bo  = out + 65536 + 8192;
        unsigned mask = 0;
        #pragma unroll
        for (int rep = 0; rep < 4; ++rep) {
            float best = -3.4e38f; int bi = 0;
            #pragma unroll
            for (int i = 0; i < 16; ++i) {
                bool ok = (((mask >> i) & 1u) == 0u) && (v[i] > best);
                if (ok) { best = v[i]; bi = i; }
            }
            mask |= (1u << bi);
            e0o[r * 4 + rep] = (float)r;
            e1o[r * 4 + rep] = (float)((r & ~15) + bi);
        }
        bo[r] = (float)(r >> 4);
    }
}

extern "C" void kernel_launch(void* const* d_in, const int* in_sizes, int n_in,
                              void* d_out, int out_size, void* d_ws, size_t ws_size,
                              hipStream_t stream)
{
    const float* x  = (const float*)d_in[0];
    const int*   e  = (const int*)d_in[1];
    const float* Wa = (const float*)d_in[3];
    const float* ba = (const float*)d_in[4];
    const float* We = (const float*)d_in[5];
    const float* be = (const float*)d_in[6];

    char* ws = (char*)d_ws;
    float* Xs     = (float*)(ws + XS_OFF);
    float* wacc   = (float*)(ws + WACC_OFF);
    float* A      = (float*)(ws + A_OFF);
    int*   cur    = (int*)(ws + CUR_OFF);
    int*   qs     = (int*)(ws + QS_OFF);
    int*   ends4  = (int*)(ws + ENDS_OFF);
    unsigned short* Sh = (unsigned short*)(ws + SH_OFF);
    unsigned* packed = (unsigned*)(ws + PK_OFF);

    k_zero    <<<82, 256, 0, stream>>>((uint4*)ws, cur);
    k_scatter <<<512, 256, 0, stream>>>(e, cur, packed);
    k_nodeSort<<<1280, 256, 0, stream>>>(x, Wa, ba, Sh, Xs, wacc, packed, cur, qs, ends4);
    k_edge    <<<2048, 256, 0, stream>>>(packed, Sh, ends4, qs, A);
    k_xt      <<<260, 256, 0, stream>>>(Xs, wacc, We, be, A, (float*)d_out);
}